// Round 10
// baseline (69955.743 us; speedup 1.0000x reference)
//
#include <hip/hip_runtime.h>
#include <math.h>

#define NB 128
#define KPH 3
#define MAXPER 48
#define MAXTOK 144
#define LATENT 128
#define HD 512
#define NMEM 8
#define NH 8
#define VOC 8000
#define CT 145
#define NBLK 512
#define SCALE 0.125f

// ---- device-coherent (agent-scope: bypass XCD L2, hit MALL) access ----
__device__ __forceinline__ float ldsc(const float* p) {
  return __hip_atomic_load(const_cast<float*>(p), __ATOMIC_RELAXED, __HIP_MEMORY_SCOPE_AGENT);
}
__device__ __forceinline__ void stsc(float* p, float v) {
  __hip_atomic_store(p, v, __ATOMIC_RELAXED, __HIP_MEMORY_SCOPE_AGENT);
}
__device__ __forceinline__ int ldsci(const int* p) {
  return __hip_atomic_load(const_cast<int*>(p), __ATOMIC_RELAXED, __HIP_MEMORY_SCOPE_AGENT);
}
__device__ __forceinline__ void stsci(int* p, int v) {
  __hip_atomic_store(p, v, __ATOMIC_RELAXED, __HIP_MEMORY_SCOPE_AGENT);
}

// global -> LDS async DMA, 4 B/lane, wave-uniform LDS base + lane*4
__device__ __forceinline__ void gload_lds(const float* g, float* l) {
  __builtin_amdgcn_global_load_lds(
      (const __attribute__((address_space(1))) unsigned int*)g,
      (__attribute__((address_space(3))) unsigned int*)l, 4, 0, 0);
}

// ======================= setup kernels (run once) ==========================

__global__ void k_zero(float* __restrict__ p, int n) {
  int i = blockIdx.x * blockDim.x + threadIdx.x;
  if (i < n) p[i] = 0.0f;
}

__global__ void k_wz(const float* __restrict__ z_seq, const float* __restrict__ zw,
                     float* __restrict__ out) {
  int i = blockIdx.x * blockDim.x + threadIdx.x;
  if (i < NB * KPH * LATENT) out[i] = zw[i >> 7] * z_seq[i];
}

__global__ void k_copy(const float* __restrict__ src, float* __restrict__ dst, int n) {
  int i = blockIdx.x * blockDim.x + threadIdx.x;
  if (i < n) dst[i] = src[i];
}

__global__ __launch_bounds__(256) void k_gemm(
    const float* __restrict__ A, int lda,
    const float* __restrict__ W, int ldw, int K,
    float* __restrict__ out, int ostride)
{
  __shared__ float As[32][36];
  __shared__ float Ws[32][64];
  const int t = threadIdx.x;
  const int c0 = blockIdx.x * 64, b0 = blockIdx.y * 32;
  const int c = t & 63, g = t >> 6;
  float acc[8] = {0,0,0,0,0,0,0,0};
  const int ra = t >> 3, ka = (t & 7) << 2;
  for (int k0 = 0; k0 < K; k0 += 32) {
    const float4 a4 = *reinterpret_cast<const float4*>(A + (size_t)(b0 + ra) * lda + k0 + ka);
    As[ra][ka] = a4.x; As[ra][ka+1] = a4.y; As[ra][ka+2] = a4.z; As[ra][ka+3] = a4.w;
    #pragma unroll
    for (int e = 0; e < 8; e++) {
      int li = t + e * 256;
      Ws[li >> 6][li & 63] = W[(size_t)(k0 + (li >> 6)) * ldw + c0 + (li & 63)];
    }
    __syncthreads();
    #pragma unroll
    for (int kk = 0; kk < 32; kk++) {
      float wv = Ws[kk][c];
      #pragma unroll
      for (int i = 0; i < 8; i++) acc[i] += As[g*8+i][kk] * wv;
    }
    __syncthreads();
  }
  #pragma unroll
  for (int i = 0; i < 8; i++)
    out[(size_t)(b0 + g * 8 + i) * ostride + c0 + c] = acc[i];
}

__global__ void k_init(const float* __restrict__ zw,
                       int* __restrict__ cur, int* __restrict__ tip, int* __restrict__ pos,
                       int* __restrict__ done, float* __restrict__ gf, int* __restrict__ iph,
                       int* __restrict__ nxt0, int* __restrict__ act)
{
  int b = blockIdx.x * blockDim.x + threadIdx.x;
  if (b < NB) {
    int a0 = zw[b*3+0] > 0.01f;
    act[b*3+0] = a0;
    act[b*3+1] = zw[b*3+1] > 0.01f;
    act[b*3+2] = zw[b*3+2] > 0.01f;
    cur[b] = 0; tip[b] = 0; pos[b] = 0; done[b] = !a0;   // version 0
    gf[b] = a0 ? 1.0f : 0.0f; iph[b] = 0;
    nxt0[b] = 1;                                          // BOS
  }
}

// ======================= persistent decode =================================

struct DecP {
  const float *temb, *Wq, *Wk, *Wv, *Wo, *Wco, *W1, *W2, *Wout;
  const float *MCK, *MCV, *WCAT;
  float *KC, *VC, *XS, *X2, *X3, *X, *Qb, *CQ, *CQ2, *H1, *GP, *PV, *GF;
  int *PI, *CUR, *TIP, *POS, *DONE, *IPH, *NXT0, *ACT;
  float *TOK, *GEN, *BND, *HID;
  unsigned *bar;
};

// hierarchical barrier: 64 arrival counters (8 blocks each); block 0 wave 0
// detects (1 counter per lane), then 8 replicated go lines; others poll one.
__device__ __forceinline__ void gsync(unsigned* bar, unsigned epoch) {
  const int t = threadIdx.x, blk = blockIdx.x;
  __syncthreads();
  if (t == 0)
    __hip_atomic_fetch_add(&bar[(blk & 63) * 32], 1u,
                           __ATOMIC_RELAXED, __HIP_MEMORY_SCOPE_AGENT);
  if (blk == 0) {
    if (t < 64) {
      const unsigned tg = epoch * (NBLK / 64);
      while (__hip_atomic_load(&bar[t * 32], __ATOMIC_RELAXED, __HIP_MEMORY_SCOPE_AGENT) < tg)
        __builtin_amdgcn_s_sleep(2);
      if (t < 8)
        __hip_atomic_store(&bar[2048 + t * 32], epoch,
                           __ATOMIC_RELAXED, __HIP_MEMORY_SCOPE_AGENT);
    }
  } else if (t == 0) {
    while (__hip_atomic_load(&bar[2048 + (blk & 7) * 32],
                             __ATOMIC_RELAXED, __HIP_MEMORY_SCOPE_AGENT) < epoch)
      __builtin_amdgcn_s_sleep(2);
  }
  __syncthreads();
}

__global__ __launch_bounds__(256, 2) void k_decode(DecP p) {
  __shared__ float Ws2[2][64][64];     // 32 KB: W slab DMA double-buffer
  __shared__ float U[8704];            // 34 KB phase-union scratch
  __shared__ int   snxt[16];

  const int t = threadIdx.x;
  const int blk = blockIdx.x;
  unsigned ep = 0;

  // 64col x 16row fp32 GEMM, K-slab 64, 4col x 1row per thread.
  // Per kk: one float4 W read (all 32 banks 2-way + 4-row broadcast) feeds
  // 4 FMAs; A read is a 4-row broadcast b32 (4 distinct banks).
  auto gemm16 = [&](int bx, int by, const float* A, int lda,
                    const float* W, int ldw, int K,
                    const float* R, int rs,
                    float* out, int os, int oo, int dogelu) {
    float (*As2)[16][72] = (float(*)[16][72])U;   // [2][16 rows][64 kk + pad]
    const int c0 = bx * 64, b0 = by * 16;
    const int c = t & 63, g = t >> 6;
    const int cg = t & 15, rg = t >> 4;           // 4 cols (cg*4), row rg
    const int sr = t & 15, sk = (t >> 4) * 4;     // A staging: row, kk-quad
    const int nslab = K >> 6;
    float acc[4] = {0,0,0,0};
    float res[4] = {0,0,0,0};
    if (R) {
      #pragma unroll
      for (int u = 0; u < 4; u++)
        res[u] = ldsc(R + (size_t)(b0 + rg) * rs + c0 + cg * 4 + u);
    }
    const float* Ab = A + (size_t)(b0 + sr) * lda + sk;
    float aP0 = ldsc(Ab + 0), aP1 = ldsc(Ab + 1), aP2 = ldsc(Ab + 2), aP3 = ldsc(Ab + 3);
    #pragma unroll
    for (int e = 0; e < 16; e++)
      gload_lds(W + (size_t)(g * 16 + e) * ldw + c0 + c, &Ws2[0][g * 16 + e][0]);
    for (int j = 0; j < nslab; j++) {
      const int cur = j & 1;
      As2[cur][sr][sk + 0] = aP0; As2[cur][sr][sk + 1] = aP1;
      As2[cur][sr][sk + 2] = aP2; As2[cur][sr][sk + 3] = aP3;
      __syncthreads();
      if (j + 1 < nslab) {
        const float* Ab2 = Ab + (j + 1) * 64;
        aP0 = ldsc(Ab2 + 0); aP1 = ldsc(Ab2 + 1); aP2 = ldsc(Ab2 + 2); aP3 = ldsc(Ab2 + 3);
        #pragma unroll
        for (int e = 0; e < 16; e++)
          gload_lds(W + (size_t)((j + 1) * 64 + g * 16 + e) * ldw + c0 + c,
                    &Ws2[cur ^ 1][g * 16 + e][0]);
      }
      #pragma unroll
      for (int kk = 0; kk < 64; kk++) {
        float4 w4 = *reinterpret_cast<const float4*>(&Ws2[cur][kk][cg * 4]);
        float a = As2[cur][rg][kk];
        acc[0] += a * w4.x; acc[1] += a * w4.y;
        acc[2] += a * w4.z; acc[3] += a * w4.w;
      }
      __syncthreads();
    }
    #pragma unroll
    for (int u = 0; u < 4; u++) {
      float v = acc[u] + res[u];
      if (dogelu) {
        float x3 = v * v * v;
        v = 0.5f * v * (1.0f + tanhf(0.7978845608028654f * (v + 0.044715f * x3)));
      }
      stsc(out + (size_t)(b0 + rg) * os + oo + c0 + cg * 4 + u, v);
    }
  };

  // gemm16 with A rows gathered from temb via snxt (for QKV)
  auto gemm16g = [&](int bx, int b0, const float* W,
                     float* out, int os, int oo) {
    float (*As2)[16][72] = (float(*)[16][72])U;
    const int c0 = bx * 64;
    const int c = t & 63, g = t >> 6;
    const int cg = t & 15, rg = t >> 4;
    const int sr = t & 15, sk = (t >> 4) * 4;
    float acc[4] = {0,0,0,0};
    const float* Ar = p.temb + (size_t)snxt[sr] * 512;
    float aP0 = Ar[sk + 0], aP1 = Ar[sk + 1], aP2 = Ar[sk + 2], aP3 = Ar[sk + 3];
    #pragma unroll
    for (int e = 0; e < 16; e++)
      gload_lds(W + (size_t)(g * 16 + e) * 512 + c0 + c, &Ws2[0][g * 16 + e][0]);
    for (int j = 0; j < 8; j++) {
      const int cur = j & 1;
      As2[cur][sr][sk + 0] = aP0; As2[cur][sr][sk + 1] = aP1;
      As2[cur][sr][sk + 2] = aP2; As2[cur][sr][sk + 3] = aP3;
      __syncthreads();
      if (j + 1 < 8) {
        const float* Ar2 = Ar + (j + 1) * 64 + sk;
        aP0 = Ar2[0]; aP1 = Ar2[1]; aP2 = Ar2[2]; aP3 = Ar2[3];
        #pragma unroll
        for (int e = 0; e < 16; e++)
          gload_lds(W + (size_t)((j + 1) * 64 + g * 16 + e) * 512 + c0 + c,
                    &Ws2[cur ^ 1][g * 16 + e][0]);
      }
      #pragma unroll
      for (int kk = 0; kk < 64; kk++) {
        float4 w4 = *reinterpret_cast<const float4*>(&Ws2[cur][kk][cg * 4]);
        float a = As2[cur][rg][kk];
        acc[0] += a * w4.x; acc[1] += a * w4.y;
        acc[2] += a * w4.z; acc[3] += a * w4.w;
      }
      __syncthreads();
    }
    #pragma unroll
    for (int u = 0; u < 4; u++)
      stsc(out + (size_t)(b0 + rg) * os + oo + c0 + cg * 4 + u, acc[u]);
  };

  // logits tile 64col x 32row, K=512, fold-R: A = X3 + GP0..3 computed inline
  // during staging (same fixed add order as the old R phase -> bit-identical);
  // bx==0 blocks also write HID[s] from the staged values. Paired-row A layout
  // (r9-verified); 4col x 2row compute; 16-lane butterfly argmax (first-index
  // tie-break exact).
  auto logits_tile = [&](int bx, int by, int s) {
    float (*AsP)[16][66][2] = (float(*)[16][66][2])U;   // [2][pair][kk+pad][2] = 4224 fl
    const int c0 = bx * 64, b0 = by * 32;
    const int c = t & 63, g = t >> 6;
    const int ar = t & 31, akb = (t >> 5) * 8;
    const int cg = t & 15, rg = t >> 4;          // 4-col group, row-pair rg
    const int desig = (bx == 0);
    float acc[2][4] = {{0,0,0,0},{0,0,0,0}};
    float aR[8];
    const size_t rowoff = (size_t)(b0 + ar) * 512 + akb;
    auto loadA = [&](int off) -> float {
      size_t el = rowoff + off;
      return ldsc(&p.X3[el]) + ldsc(&p.GP[el]) + ldsc(&p.GP[NB*512 + el])
           + ldsc(&p.GP[2*NB*512 + el]) + ldsc(&p.GP[3*NB*512 + el]);
    };
    #pragma unroll
    for (int u = 0; u < 8; u++) aR[u] = loadA(u);
    #pragma unroll
    for (int e = 0; e < 16; e++)
      gload_lds(p.Wout + (size_t)(g * 16 + e) * VOC + c0 + c, &Ws2[0][g * 16 + e][0]);
    for (int j = 0; j < 8; j++) {
      const int cur = j & 1;
      if (desig) {
        #pragma unroll
        for (int u = 0; u < 8; u++)
          p.HID[(size_t)s * NB * 512 + rowoff + j * 64 + u] = aR[u];
      }
      #pragma unroll
      for (int u = 0; u < 8; u++) AsP[cur][ar >> 1][akb + u][ar & 1] = aR[u];
      __syncthreads();
      if (j + 1 < 8) {
        #pragma unroll
        for (int u = 0; u < 8; u++) aR[u] = loadA((j + 1) * 64 + u);
        #pragma unroll
        for (int e = 0; e < 16; e++)
          gload_lds(p.Wout + (size_t)((j + 1) * 64 + g * 16 + e) * VOC + c0 + c,
                    &Ws2[cur ^ 1][g * 16 + e][0]);
      }
      #pragma unroll
      for (int kk = 0; kk < 64; kk++) {
        float4 w4 = *reinterpret_cast<const float4*>(&Ws2[cur][kk][cg * 4]);
        float2 a2 = *reinterpret_cast<const float2*>(&AsP[cur][rg][kk][0]);
        acc[0][0] += a2.x * w4.x; acc[0][1] += a2.x * w4.y;
        acc[0][2] += a2.x * w4.z; acc[0][3] += a2.x * w4.w;
        acc[1][0] += a2.y * w4.x; acc[1][1] += a2.y * w4.y;
        acc[1][2] += a2.y * w4.z; acc[1][3] += a2.y * w4.w;
      }
      __syncthreads();
    }
    #pragma unroll
    for (int i = 0; i < 2; i++) {
      float bv = acc[i][0]; int bix = c0 + cg * 4;
      #pragma unroll
      for (int u = 1; u < 4; u++) {
        float v = acc[i][u];
        if (v > bv) { bv = v; bix = c0 + cg * 4 + u; }   // ascending: first wins
      }
      #pragma unroll
      for (int off = 1; off < 16; off <<= 1) {
        float v2 = __shfl_xor(bv, off, 64);
        int   i2 = __shfl_xor(bix, off, 64);
        if (v2 > bv || (v2 == bv && i2 < bix)) { bv = v2; bix = i2; }
      }
      if (cg == 0) {
        stsc(&p.PV[(size_t)(b0 + rg * 2 + i) * 125 + bx], bv);
        stsci(&p.PI[(size_t)(b0 + rg * 2 + i) * 125 + bx], bix);
      }
    }
    __syncthreads();
  };

  // argmax-finish + state machine for rows b0..b0+15 (redundant across blocks;
  // identical values -> benign). desig block also writes outputs.
  auto state_phase = [&](int s, int b0, int desig) {
    const int r = t >> 4, j = t & 15, b = b0 + r;
    const int vOld = (s - 1) & 1, vNew = s & 1;
    if (s > 0) {
      float bv = -INFINITY; int bix = 0x7fffffff;
      for (int i = j; i < 125; i += 16) {
        float v = ldsc(&p.PV[(size_t)b * 125 + i]);
        int  id = ldsci(&p.PI[(size_t)b * 125 + i]);
        if (v > bv || (v == bv && id < bix)) { bv = v; bix = id; }
      }
      #pragma unroll
      for (int off = 8; off; off >>= 1) {
        float v2 = __shfl_xor(bv, off, 64);
        int   i2 = __shfl_xor(bix, off, 64);
        if (v2 > bv || (v2 == bv && i2 < bix)) { bv = v2; bix = i2; }
      }
      if (j == 0) {
        int nxt = bix;
        int dn = ldsci(&p.DONE[vOld*NB+b]); int live = !dn;
        int pp = ldsci(&p.POS[vOld*NB+b]);
        int tp = ldsci(&p.TIP[vOld*NB+b]);
        int cp = ldsci(&p.CUR[vOld*NB+b]);
        if (desig && pp < MAXTOK) {
          p.TOK[(size_t)b*MAXTOK+pp] = live ? (float)nxt : 0.0f;
          p.GEN[(size_t)b*MAXTOK+pp] = live ? 1.0f : 0.0f;
        }
        pp += live; tp += live;
        int eos = (nxt == 2) && (tp >= 1);
        int sw = (eos || (tp >= MAXPER)) && live;
        cp += sw;
        if (sw) tp = 0;
        int cpc = cp < 2 ? cp : 2;
        if (desig && sw && (cp < KPH)) p.BND[(size_t)b*KPH+cpc] = (float)pp;
        dn = dn || (cp >= KPH) || (sw && !p.ACT[b*3+cpc]);
        stsci(&p.CUR[vNew*NB+b], cp);
        stsci(&p.TIP[vNew*NB+b], tp);
        stsci(&p.POS[vNew*NB+b], pp);
        stsci(&p.DONE[vNew*NB+b], dn);
        stsc(&p.GF[vNew*NB+b], (p.ACT[b*3+cpc] && !dn) ? 1.0f : 0.0f);
        stsci(&p.IPH[vNew*NB+b], cpc);
        snxt[r] = nxt;
      }
    } else {
      if (j == 0) snxt[r] = p.NXT0[b];
    }
    __syncthreads();
  };

  for (int s = 0; s < MAXTOK; s++) {
    // ---- A': state (t=s-1) + Q,K,V projections (slot s); 192 blocks ----
    if (blk < 192) {
      int which = blk >> 6;                     // 0=Q 1=K 2=V
      int loc = blk & 63, bx = loc & 7, by = loc >> 3;
      int b0 = by * 16;
      int desig = (which == 0 && bx == 0);
      state_phase(s, b0, desig);
      if (desig) {                              // XS-XIN copy (16 rows)
        #pragma unroll
        for (int rep = 0; rep < 32; rep++) {
          int idx = t + rep * 256;
          int rr = idx >> 9, cc = idx & 511;
          stsc(&p.XS[(size_t)(b0 + rr) * 1024 + cc],
               p.temb[(size_t)snxt[rr] * 512 + cc]);
        }
      }
      if (which == 0)      gemm16g(bx, b0, p.Wq, p.Qb, 512, 0);
      else if (which == 1) gemm16g(bx, b0, p.Wk, p.KC, CT*512, s*512);
      else                 gemm16g(bx, b0, p.Wv, p.VC, CT*512, s*512);
    }
    gsync(p.bar, ++ep);

    // ---- B: self-attention, T = s+1, one wave per (b,h) ----
    if (blk < 256) {
      float (*aux)[224] = (float(*)[224])U;
      const int T = s + 1;
      int lane = t & 63, w = t >> 6;
      int task = blk * 4 + w, b = task >> 3, h = task & 7;
      float* ql = aux[w];
      float* sc = aux[w] + 64;
      ql[lane] = ldsc(&p.Qb[(size_t)b * 512 + h * 64 + lane]);
      __syncthreads();
      float lmax = -INFINITY;
      for (int s0 = lane; s0 < T; s0 += 64) {
        const float4* kp = reinterpret_cast<const float4*>(p.KC + ((size_t)b * CT + s0) * 512 + h * 64);
        float d = 0.0f;
        #pragma unroll
        for (int e = 0; e < 16; e++) {
          float4 k4 = kp[e];
          d += ql[4*e]*k4.x + ql[4*e+1]*k4.y + ql[4*e+2]*k4.z + ql[4*e+3]*k4.w;
        }
        d *= SCALE;
        sc[s0] = d;
        lmax = fmaxf(lmax, d);
      }
      #pragma unroll
      for (int off = 32; off; off >>= 1) lmax = fmaxf(lmax, __shfl_xor(lmax, off, 64));
      float lsum = 0.0f;
      for (int s0 = lane; s0 < T; s0 += 64) {
        float e = expf(sc[s0] - lmax);
        sc[s0] = e; lsum += e;
      }
      #pragma unroll
      for (int off = 32; off; off >>= 1) lsum += __shfl_xor(lsum, off, 64);
      __syncthreads();
      float inv = 1.0f / lsum;
      float acc = 0.0f;
      const float* vb = p.VC + (size_t)b * CT * 512 + h * 64 + lane;
      #pragma unroll 4
      for (int s0 = 0; s0 < T; s0++) acc += sc[s0] * vb[(size_t)s0 * 512];
      stsc(&p.XS[(size_t)b * 1024 + 512 + h * 64 + lane], acc * inv);
    }
    gsync(p.bar, ++ep);

    // ---- C: X2 = XIN + SA@Wo ; CQ/CQ2 = WCAT split-K2 (192 blocks) ----
    if (blk < 64)
      gemm16(blk & 7, blk >> 3, p.XS + 512, 1024, p.Wo, 512, 512, p.XS, 1024, p.X2, 512, 0, 0);
    else if (blk < 128) {
      int l = blk - 64;
      gemm16(l & 7, l >> 3, p.XS, 1024, p.WCAT, 512, 512, nullptr, 0, p.CQ, 512, 0, 0);
    } else if (blk < 192) {
      int l = blk - 128;
      gemm16(l & 7, l >> 3, p.XS + 512, 1024, p.WCAT + (size_t)512*512, 512, 512,
             nullptr, 0, p.CQ2, 512, 0, 0);
    }
    gsync(p.bar, ++ep);

    // ---- E': fused cross-attention + X3 = X2 + CA@Wco, one block per b ----
    if (blk < NB) {
      const int b = blk;
      const int vNew = s & 1;
      float* cq  = U;            // 512
      float* ca  = U + 512;      // 512
      float* scs = U + 1024;     // 64
      cq[t]       = ldsc(&p.CQ[(size_t)b * 512 + t])       + ldsc(&p.CQ2[(size_t)b * 512 + t]);
      cq[t + 256] = ldsc(&p.CQ[(size_t)b * 512 + t + 256]) + ldsc(&p.CQ2[(size_t)b * 512 + t + 256]);
      __syncthreads();
      float gate = ldsc(&p.GF[vNew*NB+b]);
      int ip = ldsci(&p.IPH[vNew*NB+b]);
      const float* mk = p.MCK + (size_t)(b * KPH + ip) * NMEM * 512;
      if (t < 64) {
        int h = t >> 3, m = t & 7;
        const float4* kp = reinterpret_cast<const float4*>(mk + m * 512 + h * 64);
        float d = 0.0f;
        #pragma unroll
        for (int e = 0; e < 16; e++) {
          float4 k4 = kp[e];
          d += cq[h*64+4*e]*k4.x + cq[h*64+4*e+1]*k4.y + cq[h*64+4*e+2]*k4.z + cq[h*64+4*e+3]*k4.w;
        }
        scs[t] = d * SCALE * gate;
      }
      __syncthreads();
      const float* mv = p.MCV + (size_t)(b * KPH + ip) * NMEM * 512;
      #pragma unroll
      for (int half = 0; half < 2; half++) {
        int c = t + half * 256;
        int h = c >> 6;
        float mx = scs[h*8];
        #pragma unroll
        for (int m = 1; m < 8; m++) mx = fmaxf(mx, scs[h*8+m]);
        float ee[8]; float sum = 0.0f;
        #pragma unroll
        for (int m = 0; m < 8; m++) { ee[m] = expf(scs[h*8+m] - mx); sum += ee[m]; }
        float a = 0.0f;
        #pragma unroll
        for (int m = 0; m < 8; m++) a += ee[m] * mv[(size_t)m * 512 + c];
        ca[c] = gate * a / sum;
      }
      __syncthreads();
      // X3[b][c] = X2[b][c] + sum_k ca[k]*Wco[k][c]   (serial k, fixed order)
      #pragma unroll
      for (int half = 0; half < 2; half++) {
        int c = t + half * 256;
        float acc = 0.0f;
        const float* wc = p.Wco + c;
        #pragma unroll 8
        for (int k = 0; k < 512; k++) acc += ca[k] * wc[(size_t)k * 512];
        stsc(&p.X3[(size_t)b * 512 + c], acc + ldsc(&p.X2[(size_t)b * 512 + c]));
      }
    }
    gsync(p.bar, ++ep);

    // ---- F: H1 = gelu(X3@W1), N=2048, 256 blocks (32ct x 8rt) ----
    if (blk < 256)
      gemm16(blk & 31, blk >> 5, p.X3, 512, p.W1, 2048, 512, nullptr, 0, p.H1, 2048, 0, 1);
    gsync(p.bar, ++ep);

    // ---- G: GP[ks] = H1[:,ks*512:+512] @ W2[ks*512:+512,:], split-K4, 256 blk ----
    if (blk < 256) {
      int ks = blk >> 6, loc = blk & 63;
      gemm16(loc & 7, loc >> 3, p.H1 + ks * 512, 2048,
             p.W2 + (size_t)ks * 512 * 512, 512, 512,
             nullptr, 0, p.GP + (size_t)ks * NB * 512, 512, 0, 0);
    }
    gsync(p.bar, ++ep);

    // ---- H: logits (A = X3+ΣGP inline; bx==0 writes HID[s]) + argmax
    //      partials; col tiles XCD-pinned (bx%8==blk%8) ----
    {
      const int x = blk & 7, idx2 = blk >> 3;
      const int ii = idx2 & 15, by = idx2 >> 4;
      const int bx = x + 8 * ii;
      if (bx < 125) logits_tile(bx, by, s);
    }
    gsync(p.bar, ++ep);
  }

  // ---- epilogue: state machine t=143 + final TOK/GEN/BND ----
  if (blk < 128 && (blk & 15) == 0) {
    const int b0 = (blk >> 4) * 16;
    state_phase(MAXTOK, b0, 1);
  }
}

// ======================= host ==============================================

extern "C" void kernel_launch(void* const* d_in, const int* in_sizes, int n_in,
                              void* d_out, int out_size, void* d_ws, size_t ws_size,
                              hipStream_t stream)
{
  const float* z_seq = (const float*)d_in[0];
  const float* z_w   = (const float*)d_in[1];
  const float* W_l2d = (const float*)d_in[2];
  const float* temb  = (const float*)d_in[3];
  const float* Wq  = (const float*)d_in[4];
  const float* Wk  = (const float*)d_in[5];
  const float* Wv  = (const float*)d_in[6];
  const float* Wo  = (const float*)d_in[7];
  const float* Wcq = (const float*)d_in[8];
  const float* Wck = (const float*)d_in[9];
  const float* Wcv = (const float*)d_in[10];
  const float* Wco = (const float*)d_in[11];
  const float* W1  = (const float*)d_in[12];
  const float* W2  = (const float*)d_in[13];
  const float* Wout= (const float*)d_in[14];

  float* fw = (float*)d_ws;
  size_t o = 4096;   // first 4096 words: barrier counters + go lines
  auto alloc = [&](size_t n) { float* r = fw + o; o += (n + 63) & ~(size_t)63; return r; };
  float* MCK = alloc((size_t)NB*KPH*NMEM*HD);
  float* MCV = alloc((size_t)NB*KPH*NMEM*HD);
  float* MEM = alloc((size_t)NB*KPH*NMEM*HD);   // reused as WCAT + GP/CQ2 after setup
  float* KC  = alloc((size_t)NB*CT*HD);
  float* VC  = alloc((size_t)NB*CT*HD);
  float* XS  = alloc((size_t)NB*1024);          // [XIN | SA]
  float* X2  = alloc((size_t)NB*HD);
  float* X3  = alloc((size_t)NB*HD);
  float* X   = alloc((size_t)NB*HD);
  float* Qb  = alloc((size_t)NB*HD);
  float* CQ  = alloc((size_t)NB*HD);
  float* H1  = alloc((size_t)NB*4*HD);
  float* WZ  = alloc((size_t)NB*KPH*LATENT);
  float* PV  = alloc((size_t)NB*125);
  float* GF  = alloc(2*NB);
  int* ib = (int*)alloc(0);
  size_t io = 0;
  auto ialloc = [&](size_t n) { int* r = ib + io; io += (n + 63) & ~(size_t)63; return r; };
  int* PI   = ialloc((size_t)NB*125);
  int* CUR  = ialloc(2*NB);
  int* TIP  = ialloc(2*NB);
  int* POS  = ialloc(2*NB);
  int* DONE = ialloc(2*NB);
  int* IPH  = ialloc(2*NB);
  int* NXT0 = ialloc(NB);
  int* ACT  = ialloc(NB*KPH);

  // MEM region (1,572,864 floats) layout after setup:
  //   [0 .. 524288)        WCAT = [Wcq ; Wo@Wcq]  (1024 x 512)
  //   [524288 .. 786432)   GP   (4 * NB * HD floats, split-K4 partials)
  //   [786432 .. 851968)   CQ2  (NB * HD floats, split-K2 partial)
  float* WCAT = MEM;
  float* GP   = MEM + (size_t)1024*512;
  float* CQ2  = GP  + (size_t)4*NB*HD;

  float* out_f = (float*)d_out;
  float* TOK  = out_f;
  float* GEN  = out_f + NB*MAXTOK;
  float* BND  = out_f + 2*NB*MAXTOK;
  float* HID  = out_f + 2*NB*MAXTOK + NB*KPH;

  // ---- one-time setup (plain kernels; dispatch boundaries give coherence) ----
  k_zero<<<16, 256, 0, stream>>>(fw, 4096);                               // barrier
  int nz = 2*NB*MAXTOK + NB*KPH;
  k_zero<<<(nz + 255)/256, 256, 0, stream>>>(out_f, nz);                  // tok/gen/bnd
  k_wz<<<(NB*KPH*LATENT + 255)/256, 256, 0, stream>>>(z_seq, z_w, WZ);
  k_gemm<<<dim3(64,12),256,0,stream>>>(WZ, 128, W_l2d, 4096, 128, MEM, 4096);
  k_gemm<<<dim3(8,96),256,0,stream>>>(MEM, 512, Wck, 512, 512, MCK, 512);
  k_gemm<<<dim3(8,96),256,0,stream>>>(MEM, 512, Wcv, 512, 512, MCV, 512);
  k_gemm<<<dim3(8,16),256,0,stream>>>(Wo, 512, Wcq, 512, 512, WCAT + (size_t)512*512, 512);
  k_copy<<<(512*512 + 255)/256, 256, 0, stream>>>(Wcq, WCAT, 512*512);
  k_init<<<1,128,0,stream>>>(z_w, CUR, TIP, POS, DONE, GF, IPH, NXT0, ACT);

  // ---- persistent decode: plain launch; 512 blocks, 2/CU co-resident ----
  DecP prm;
  prm.temb = temb; prm.Wq = Wq; prm.Wk = Wk; prm.Wv = Wv; prm.Wo = Wo;
  prm.Wco = Wco; prm.W1 = W1; prm.W2 = W2; prm.Wout = Wout;
  prm.MCK = MCK; prm.MCV = MCV; prm.WCAT = WCAT;
  prm.KC = KC; prm.VC = VC; prm.XS = XS; prm.X2 = X2; prm.X3 = X3; prm.X = X;
  prm.Qb = Qb; prm.CQ = CQ; prm.CQ2 = CQ2; prm.H1 = H1; prm.GP = GP;
  prm.PV = PV; prm.GF = GF;
  prm.PI = PI; prm.CUR = CUR; prm.TIP = TIP; prm.POS = POS; prm.DONE = DONE;
  prm.IPH = IPH; prm.NXT0 = NXT0; prm.ACT = ACT;
  prm.TOK = TOK; prm.GEN = GEN; prm.BND = BND; prm.HID = HID;
  prm.bar = (unsigned*)d_ws;

  k_decode<<<dim3(NBLK), dim3(256), 0, stream>>>(prm);
}

// Round 12
// 27639.648 us; speedup vs baseline: 2.5310x; 2.5310x over previous
//
#include <hip/hip_runtime.h>
#include <math.h>

#define NB 128
#define KPH 3
#define MAXPER 48
#define MAXTOK 144
#define LATENT 128
#define HD 512
#define NMEM 8
#define NH 8
#define VOC 8000
#define CT 145
#define NBLK 512
#define SCALE 0.125f

// ---- device-coherent (agent-scope: bypass XCD L2, hit MALL) access ----
__device__ __forceinline__ float ldsc(const float* p) {
  return __hip_atomic_load(const_cast<float*>(p), __ATOMIC_RELAXED, __HIP_MEMORY_SCOPE_AGENT);
}
__device__ __forceinline__ void stsc(float* p, float v) {
  __hip_atomic_store(p, v, __ATOMIC_RELAXED, __HIP_MEMORY_SCOPE_AGENT);
}
__device__ __forceinline__ int ldsci(const int* p) {
  return __hip_atomic_load(const_cast<int*>(p), __ATOMIC_RELAXED, __HIP_MEMORY_SCOPE_AGENT);
}
__device__ __forceinline__ void stsci(int* p, int v) {
  __hip_atomic_store(p, v, __ATOMIC_RELAXED, __HIP_MEMORY_SCOPE_AGENT);
}

// global -> LDS async DMA, 4 B/lane, wave-uniform LDS base + lane*4
__device__ __forceinline__ void gload_lds(const float* g, float* l) {
  __builtin_amdgcn_global_load_lds(
      (const __attribute__((address_space(1))) unsigned int*)g,
      (__attribute__((address_space(3))) unsigned int*)l, 4, 0, 0);
}

// ======================= setup kernels (run once) ==========================

__global__ void k_zero(float* __restrict__ p, int n) {
  int i = blockIdx.x * blockDim.x + threadIdx.x;
  if (i < n) p[i] = 0.0f;
}

__global__ void k_wz(const float* __restrict__ z_seq, const float* __restrict__ zw,
                     float* __restrict__ out) {
  int i = blockIdx.x * blockDim.x + threadIdx.x;
  if (i < NB * KPH * LATENT) out[i] = zw[i >> 7] * z_seq[i];
}

__global__ void k_copy(const float* __restrict__ src, float* __restrict__ dst, int n) {
  int i = blockIdx.x * blockDim.x + threadIdx.x;
  if (i < n) dst[i] = src[i];
}

__global__ __launch_bounds__(256) void k_gemm(
    const float* __restrict__ A, int lda,
    const float* __restrict__ W, int ldw, int K,
    float* __restrict__ out, int ostride)
{
  __shared__ float As[32][36];
  __shared__ float Ws[32][64];
  const int t = threadIdx.x;
  const int c0 = blockIdx.x * 64, b0 = blockIdx.y * 32;
  const int c = t & 63, g = t >> 6;
  float acc[8] = {0,0,0,0,0,0,0,0};
  const int ra = t >> 3, ka = (t & 7) << 2;
  for (int k0 = 0; k0 < K; k0 += 32) {
    const float4 a4 = *reinterpret_cast<const float4*>(A + (size_t)(b0 + ra) * lda + k0 + ka);
    As[ra][ka] = a4.x; As[ra][ka+1] = a4.y; As[ra][ka+2] = a4.z; As[ra][ka+3] = a4.w;
    #pragma unroll
    for (int e = 0; e < 8; e++) {
      int li = t + e * 256;
      Ws[li >> 6][li & 63] = W[(size_t)(k0 + (li >> 6)) * ldw + c0 + (li & 63)];
    }
    __syncthreads();
    #pragma unroll
    for (int kk = 0; kk < 32; kk++) {
      float wv = Ws[kk][c];
      #pragma unroll
      for (int i = 0; i < 8; i++) acc[i] += As[g*8+i][kk] * wv;
    }
    __syncthreads();
  }
  #pragma unroll
  for (int i = 0; i < 8; i++)
    out[(size_t)(b0 + g * 8 + i) * ostride + c0 + c] = acc[i];
}

__global__ void k_init(const float* __restrict__ zw,
                       int* __restrict__ cur, int* __restrict__ tip, int* __restrict__ pos,
                       int* __restrict__ done, float* __restrict__ gf, int* __restrict__ iph,
                       int* __restrict__ nxt0, int* __restrict__ act)
{
  int b = blockIdx.x * blockDim.x + threadIdx.x;
  if (b < NB) {
    int a0 = zw[b*3+0] > 0.01f;
    act[b*3+0] = a0;
    act[b*3+1] = zw[b*3+1] > 0.01f;
    act[b*3+2] = zw[b*3+2] > 0.01f;
    cur[b] = 0; tip[b] = 0; pos[b] = 0; done[b] = !a0;   // version 0
    gf[b] = a0 ? 1.0f : 0.0f; iph[b] = 0;
    nxt0[b] = 1;                                          // BOS
  }
}

// ======================= persistent decode =================================

struct DecP {
  const float *temb, *Wq, *Wk, *Wv, *Wo, *Wco, *W1, *W2, *Wout;
  const float *MCK, *MCV, *WCAT;
  float *KC, *VC, *XS, *X2, *X3, *X, *Qb, *CQ, *CQ2, *H1, *GP, *PV, *GF;
  int *PI, *CUR, *TIP, *POS, *DONE, *IPH, *NXT0, *ACT;
  float *TOK, *GEN, *BND, *HID;
  unsigned *bar;
};

// hierarchical barrier: 64 arrival counters (8 blocks each); block 0 wave 0
// detects (1 counter per lane), then 8 replicated go lines; others poll one.
__device__ __forceinline__ void gsync(unsigned* bar, unsigned epoch) {
  const int t = threadIdx.x, blk = blockIdx.x;
  __syncthreads();
  if (t == 0)
    __hip_atomic_fetch_add(&bar[(blk & 63) * 32], 1u,
                           __ATOMIC_RELAXED, __HIP_MEMORY_SCOPE_AGENT);
  if (blk == 0) {
    if (t < 64) {
      const unsigned tg = epoch * (NBLK / 64);
      while (__hip_atomic_load(&bar[t * 32], __ATOMIC_RELAXED, __HIP_MEMORY_SCOPE_AGENT) < tg)
        __builtin_amdgcn_s_sleep(2);
      if (t < 8)
        __hip_atomic_store(&bar[2048 + t * 32], epoch,
                           __ATOMIC_RELAXED, __HIP_MEMORY_SCOPE_AGENT);
    }
  } else if (t == 0) {
    while (__hip_atomic_load(&bar[2048 + (blk & 7) * 32],
                             __ATOMIC_RELAXED, __HIP_MEMORY_SCOPE_AGENT) < epoch)
      __builtin_amdgcn_s_sleep(8);
  }
  __syncthreads();
}

__global__ __launch_bounds__(256, 2) void k_decode(DecP p) {
  __shared__ float Ws2[2][64][64];     // 32 KB: W slab DMA double-buffer
  __shared__ float U[8704];            // 34 KB phase-union scratch
  __shared__ int   snxt[16];

  const int t = threadIdx.x;
  const int blk = blockIdx.x;
  unsigned ep = 0;

  // 64col x 16row fp32 GEMM, K-slab 64, 4col x 1row per thread.
  // Per kk: one float4 W read (all 32 banks 2-way + 4-row broadcast) feeds
  // 4 FMAs; A read is a 4-row broadcast b32 (4 distinct banks).
  auto gemm16 = [&](int bx, int by, const float* A, int lda,
                    const float* W, int ldw, int K,
                    const float* R, int rs,
                    float* out, int os, int oo, int dogelu) {
    float (*As2)[16][72] = (float(*)[16][72])U;   // [2][16 rows][64 kk + pad]
    const int c0 = bx * 64, b0 = by * 16;
    const int c = t & 63, g = t >> 6;
    const int cg = t & 15, rg = t >> 4;           // 4 cols (cg*4), row rg
    const int sr = t & 15, sk = (t >> 4) * 4;     // A staging: row, kk-quad
    const int nslab = K >> 6;
    float acc[4] = {0,0,0,0};
    float res[4] = {0,0,0,0};
    if (R) {
      #pragma unroll
      for (int u = 0; u < 4; u++)
        res[u] = ldsc(R + (size_t)(b0 + rg) * rs + c0 + cg * 4 + u);
    }
    const float* Ab = A + (size_t)(b0 + sr) * lda + sk;
    float aP0 = ldsc(Ab + 0), aP1 = ldsc(Ab + 1), aP2 = ldsc(Ab + 2), aP3 = ldsc(Ab + 3);
    #pragma unroll
    for (int e = 0; e < 16; e++)
      gload_lds(W + (size_t)(g * 16 + e) * ldw + c0 + c, &Ws2[0][g * 16 + e][0]);
    for (int j = 0; j < nslab; j++) {
      const int cur = j & 1;
      As2[cur][sr][sk + 0] = aP0; As2[cur][sr][sk + 1] = aP1;
      As2[cur][sr][sk + 2] = aP2; As2[cur][sr][sk + 3] = aP3;
      __syncthreads();
      if (j + 1 < nslab) {
        const float* Ab2 = Ab + (j + 1) * 64;
        aP0 = ldsc(Ab2 + 0); aP1 = ldsc(Ab2 + 1); aP2 = ldsc(Ab2 + 2); aP3 = ldsc(Ab2 + 3);
        #pragma unroll
        for (int e = 0; e < 16; e++)
          gload_lds(W + (size_t)((j + 1) * 64 + g * 16 + e) * ldw + c0 + c,
                    &Ws2[cur ^ 1][g * 16 + e][0]);
      }
      #pragma unroll
      for (int kk = 0; kk < 64; kk++) {
        float4 w4 = *reinterpret_cast<const float4*>(&Ws2[cur][kk][cg * 4]);
        float a = As2[cur][rg][kk];
        acc[0] += a * w4.x; acc[1] += a * w4.y;
        acc[2] += a * w4.z; acc[3] += a * w4.w;
      }
      __syncthreads();
    }
    #pragma unroll
    for (int u = 0; u < 4; u++) {
      float v = acc[u] + res[u];
      if (dogelu) {
        float x3 = v * v * v;
        v = 0.5f * v * (1.0f + tanhf(0.7978845608028654f * (v + 0.044715f * x3)));
      }
      stsc(out + (size_t)(b0 + rg) * os + oo + c0 + cg * 4 + u, v);
    }
  };

  // gemm16 with A rows gathered from temb via snxt (for QKV)
  auto gemm16g = [&](int bx, int b0, const float* W,
                     float* out, int os, int oo) {
    float (*As2)[16][72] = (float(*)[16][72])U;
    const int c0 = bx * 64;
    const int c = t & 63, g = t >> 6;
    const int cg = t & 15, rg = t >> 4;
    const int sr = t & 15, sk = (t >> 4) * 4;
    float acc[4] = {0,0,0,0};
    const float* Ar = p.temb + (size_t)snxt[sr] * 512;
    float aP0 = Ar[sk + 0], aP1 = Ar[sk + 1], aP2 = Ar[sk + 2], aP3 = Ar[sk + 3];
    #pragma unroll
    for (int e = 0; e < 16; e++)
      gload_lds(W + (size_t)(g * 16 + e) * 512 + c0 + c, &Ws2[0][g * 16 + e][0]);
    for (int j = 0; j < 8; j++) {
      const int cur = j & 1;
      As2[cur][sr][sk + 0] = aP0; As2[cur][sr][sk + 1] = aP1;
      As2[cur][sr][sk + 2] = aP2; As2[cur][sr][sk + 3] = aP3;
      __syncthreads();
      if (j + 1 < 8) {
        const float* Ar2 = Ar + (j + 1) * 64 + sk;
        aP0 = Ar2[0]; aP1 = Ar2[1]; aP2 = Ar2[2]; aP3 = Ar2[3];
        #pragma unroll
        for (int e = 0; e < 16; e++)
          gload_lds(W + (size_t)((j + 1) * 64 + g * 16 + e) * 512 + c0 + c,
                    &Ws2[cur ^ 1][g * 16 + e][0]);
      }
      #pragma unroll
      for (int kk = 0; kk < 64; kk++) {
        float4 w4 = *reinterpret_cast<const float4*>(&Ws2[cur][kk][cg * 4]);
        float a = As2[cur][rg][kk];
        acc[0] += a * w4.x; acc[1] += a * w4.y;
        acc[2] += a * w4.z; acc[3] += a * w4.w;
      }
      __syncthreads();
    }
    #pragma unroll
    for (int u = 0; u < 4; u++)
      stsc(out + (size_t)(b0 + rg) * os + oo + c0 + cg * 4 + u, acc[u]);
  };

  // logits tile 64col x 32row, K=512. A staged as row-PAIRS [rowpair][kk][2]
  // (stride 66*2 floats) so the per-kk two row-reads are one b64 broadcast,
  // contiguous across kk (compiler-batchable to b128). 4col x 2row per thread
  // via float4 W reads; in-register 16-lane butterfly argmax (first-index
  // tie-break exact).
  auto logits_tile = [&](int bx, int by) {
    float (*AsP)[16][66][2] = (float(*)[16][66][2])U;   // [2][pair][kk+pad][2] = 4224 fl
    const int c0 = bx * 64, b0 = by * 32;
    const int c = t & 63, g = t >> 6;
    const int ar = t & 31, akb = (t >> 5) * 8;
    const int cg = t & 15, rg = t >> 4;          // 4-col group, row-pair rg
    float acc[2][4] = {{0,0,0,0},{0,0,0,0}};
    float aR[8];
    const float* Ab = p.X + (size_t)(b0 + ar) * 512 + akb;
    #pragma unroll
    for (int u = 0; u < 8; u++) aR[u] = ldsc(Ab + u);
    #pragma unroll
    for (int e = 0; e < 16; e++)
      gload_lds(p.Wout + (size_t)(g * 16 + e) * VOC + c0 + c, &Ws2[0][g * 16 + e][0]);
    for (int j = 0; j < 8; j++) {
      const int cur = j & 1;
      #pragma unroll
      for (int u = 0; u < 8; u++) AsP[cur][ar >> 1][akb + u][ar & 1] = aR[u];
      __syncthreads();
      if (j + 1 < 8) {
        #pragma unroll
        for (int u = 0; u < 8; u++) aR[u] = ldsc(Ab + (j + 1) * 64 + u);
        #pragma unroll
        for (int e = 0; e < 16; e++)
          gload_lds(p.Wout + (size_t)((j + 1) * 64 + g * 16 + e) * VOC + c0 + c,
                    &Ws2[cur ^ 1][g * 16 + e][0]);
      }
      #pragma unroll
      for (int kk = 0; kk < 64; kk++) {
        float4 w4 = *reinterpret_cast<const float4*>(&Ws2[cur][kk][cg * 4]);
        float2 a2 = *reinterpret_cast<const float2*>(&AsP[cur][rg][kk][0]);
        acc[0][0] += a2.x * w4.x; acc[0][1] += a2.x * w4.y;
        acc[0][2] += a2.x * w4.z; acc[0][3] += a2.x * w4.w;
        acc[1][0] += a2.y * w4.x; acc[1][1] += a2.y * w4.y;
        acc[1][2] += a2.y * w4.z; acc[1][3] += a2.y * w4.w;
      }
      __syncthreads();
    }
    #pragma unroll
    for (int i = 0; i < 2; i++) {
      float bv = acc[i][0]; int bix = c0 + cg * 4;
      #pragma unroll
      for (int u = 1; u < 4; u++) {
        float v = acc[i][u];
        if (v > bv) { bv = v; bix = c0 + cg * 4 + u; }   // ascending: first wins
      }
      #pragma unroll
      for (int off = 1; off < 16; off <<= 1) {
        float v2 = __shfl_xor(bv, off, 64);
        int   i2 = __shfl_xor(bix, off, 64);
        if (v2 > bv || (v2 == bv && i2 < bix)) { bv = v2; bix = i2; }
      }
      if (cg == 0) {
        stsc(&p.PV[(size_t)(b0 + rg * 2 + i) * 125 + bx], bv);
        stsci(&p.PI[(size_t)(b0 + rg * 2 + i) * 125 + bx], bix);
      }
    }
    __syncthreads();
  };

  // argmax-finish + state machine for rows b0..b0+15 (redundant across blocks;
  // identical values -> benign). desig block also writes outputs.
  auto state_phase = [&](int s, int b0, int desig) {
    const int r = t >> 4, j = t & 15, b = b0 + r;
    const int vOld = (s - 1) & 1, vNew = s & 1;
    if (s > 0) {
      float bv = -INFINITY; int bix = 0x7fffffff;
      for (int i = j; i < 125; i += 16) {
        float v = ldsc(&p.PV[(size_t)b * 125 + i]);
        int  id = ldsci(&p.PI[(size_t)b * 125 + i]);
        if (v > bv || (v == bv && id < bix)) { bv = v; bix = id; }
      }
      #pragma unroll
      for (int off = 8; off; off >>= 1) {
        float v2 = __shfl_xor(bv, off, 64);
        int   i2 = __shfl_xor(bix, off, 64);
        if (v2 > bv || (v2 == bv && i2 < bix)) { bv = v2; bix = i2; }
      }
      if (j == 0) {
        int nxt = bix;
        int dn = ldsci(&p.DONE[vOld*NB+b]); int live = !dn;
        int pp = ldsci(&p.POS[vOld*NB+b]);
        int tp = ldsci(&p.TIP[vOld*NB+b]);
        int cp = ldsci(&p.CUR[vOld*NB+b]);
        if (desig && pp < MAXTOK) {
          p.TOK[(size_t)b*MAXTOK+pp] = live ? (float)nxt : 0.0f;
          p.GEN[(size_t)b*MAXTOK+pp] = live ? 1.0f : 0.0f;
        }
        pp += live; tp += live;
        int eos = (nxt == 2) && (tp >= 1);
        int sw = (eos || (tp >= MAXPER)) && live;
        cp += sw;
        if (sw) tp = 0;
        int cpc = cp < 2 ? cp : 2;
        if (desig && sw && (cp < KPH)) p.BND[(size_t)b*KPH+cpc] = (float)pp;
        dn = dn || (cp >= KPH) || (sw && !p.ACT[b*3+cpc]);
        stsci(&p.CUR[vNew*NB+b], cp);
        stsci(&p.TIP[vNew*NB+b], tp);
        stsci(&p.POS[vNew*NB+b], pp);
        stsci(&p.DONE[vNew*NB+b], dn);
        stsc(&p.GF[vNew*NB+b], (p.ACT[b*3+cpc] && !dn) ? 1.0f : 0.0f);
        stsci(&p.IPH[vNew*NB+b], cpc);
        snxt[r] = nxt;
      }
    } else {
      if (j == 0) snxt[r] = p.NXT0[b];
    }
    __syncthreads();
  };

  for (int s = 0; s < MAXTOK; s++) {
    // ---- A': state (t=s-1) + Q,K,V projections (slot s); 192 blocks ----
    if (blk < 192) {
      int which = blk >> 6;                     // 0=Q 1=K 2=V
      int loc = blk & 63, bx = loc & 7, by = loc >> 3;
      int b0 = by * 16;
      int desig = (which == 0 && bx == 0);
      state_phase(s, b0, desig);
      if (desig) {                              // XS-XIN copy (16 rows)
        #pragma unroll
        for (int rep = 0; rep < 32; rep++) {
          int idx = t + rep * 256;
          int rr = idx >> 9, cc = idx & 511;
          stsc(&p.XS[(size_t)(b0 + rr) * 1024 + cc],
               p.temb[(size_t)snxt[rr] * 512 + cc]);
        }
      }
      if (which == 0)      gemm16g(bx, b0, p.Wq, p.Qb, 512, 0);
      else if (which == 1) gemm16g(bx, b0, p.Wk, p.KC, CT*512, s*512);
      else                 gemm16g(bx, b0, p.Wv, p.VC, CT*512, s*512);
    }
    gsync(p.bar, ++ep);

    // ---- B: self-attention, T = s+1, one wave per (b,h) ----
    if (blk < 256) {
      float (*aux)[224] = (float(*)[224])U;
      const int T = s + 1;
      int lane = t & 63, w = t >> 6;
      int task = blk * 4 + w, b = task >> 3, h = task & 7;
      float* ql = aux[w];
      float* sc = aux[w] + 64;
      ql[lane] = ldsc(&p.Qb[(size_t)b * 512 + h * 64 + lane]);
      __syncthreads();
      float lmax = -INFINITY;
      for (int s0 = lane; s0 < T; s0 += 64) {
        const float4* kp = reinterpret_cast<const float4*>(p.KC + ((size_t)b * CT + s0) * 512 + h * 64);
        float d = 0.0f;
        #pragma unroll
        for (int e = 0; e < 16; e++) {
          float4 k4 = kp[e];
          d += ql[4*e]*k4.x + ql[4*e+1]*k4.y + ql[4*e+2]*k4.z + ql[4*e+3]*k4.w;
        }
        d *= SCALE;
        sc[s0] = d;
        lmax = fmaxf(lmax, d);
      }
      #pragma unroll
      for (int off = 32; off; off >>= 1) lmax = fmaxf(lmax, __shfl_xor(lmax, off, 64));
      float lsum = 0.0f;
      for (int s0 = lane; s0 < T; s0 += 64) {
        float e = expf(sc[s0] - lmax);
        sc[s0] = e; lsum += e;
      }
      #pragma unroll
      for (int off = 32; off; off >>= 1) lsum += __shfl_xor(lsum, off, 64);
      __syncthreads();
      float inv = 1.0f / lsum;
      float acc = 0.0f;
      const float* vb = p.VC + (size_t)b * CT * 512 + h * 64 + lane;
      #pragma unroll 4
      for (int s0 = 0; s0 < T; s0++) acc += sc[s0] * vb[(size_t)s0 * 512];
      stsc(&p.XS[(size_t)b * 1024 + 512 + h * 64 + lane], acc * inv);
    }
    gsync(p.bar, ++ep);

    // ---- C: X2 = XIN + SA@Wo ; CQ/CQ2 = WCAT split-K2 (192 blocks) ----
    if (blk < 64)
      gemm16(blk & 7, blk >> 3, p.XS + 512, 1024, p.Wo, 512, 512, p.XS, 1024, p.X2, 512, 0, 0);
    else if (blk < 128) {
      int l = blk - 64;
      gemm16(l & 7, l >> 3, p.XS, 1024, p.WCAT, 512, 512, nullptr, 0, p.CQ, 512, 0, 0);
    } else if (blk < 192) {
      int l = blk - 128;
      gemm16(l & 7, l >> 3, p.XS + 512, 1024, p.WCAT + (size_t)512*512, 512, 512,
             nullptr, 0, p.CQ2, 512, 0, 0);
    }
    gsync(p.bar, ++ep);

    // ---- E': fused cross-attention + X3 = X2 + CA@Wco, one block per b ----
    if (blk < NB) {
      const int b = blk;
      const int vNew = s & 1;
      float* cq  = U;            // 512
      float* ca  = U + 512;      // 512
      float* scs = U + 1024;     // 64
      cq[t]       = ldsc(&p.CQ[(size_t)b * 512 + t])       + ldsc(&p.CQ2[(size_t)b * 512 + t]);
      cq[t + 256] = ldsc(&p.CQ[(size_t)b * 512 + t + 256]) + ldsc(&p.CQ2[(size_t)b * 512 + t + 256]);
      __syncthreads();
      float gate = ldsc(&p.GF[vNew*NB+b]);
      int ip = ldsci(&p.IPH[vNew*NB+b]);
      const float* mk = p.MCK + (size_t)(b * KPH + ip) * NMEM * 512;
      if (t < 64) {
        int h = t >> 3, m = t & 7;
        const float4* kp = reinterpret_cast<const float4*>(mk + m * 512 + h * 64);
        float d = 0.0f;
        #pragma unroll
        for (int e = 0; e < 16; e++) {
          float4 k4 = kp[e];
          d += cq[h*64+4*e]*k4.x + cq[h*64+4*e+1]*k4.y + cq[h*64+4*e+2]*k4.z + cq[h*64+4*e+3]*k4.w;
        }
        scs[t] = d * SCALE * gate;
      }
      __syncthreads();
      const float* mv = p.MCV + (size_t)(b * KPH + ip) * NMEM * 512;
      #pragma unroll
      for (int half = 0; half < 2; half++) {
        int c = t + half * 256;
        int h = c >> 6;
        float mx = scs[h*8];
        #pragma unroll
        for (int m = 1; m < 8; m++) mx = fmaxf(mx, scs[h*8+m]);
        float ee[8]; float sum = 0.0f;
        #pragma unroll
        for (int m = 0; m < 8; m++) { ee[m] = expf(scs[h*8+m] - mx); sum += ee[m]; }
        float a = 0.0f;
        #pragma unroll
        for (int m = 0; m < 8; m++) a += ee[m] * mv[(size_t)m * 512 + c];
        ca[c] = gate * a / sum;
      }
      __syncthreads();
      // X3[b][c] = X2[b][c] + sum_k ca[k]*Wco[k][c]   (serial k, fixed order)
      #pragma unroll
      for (int half = 0; half < 2; half++) {
        int c = t + half * 256;
        float acc = 0.0f;
        const float* wc = p.Wco + c;
        #pragma unroll 8
        for (int k = 0; k < 512; k++) acc += ca[k] * wc[(size_t)k * 512];
        stsc(&p.X3[(size_t)b * 512 + c], acc + ldsc(&p.X2[(size_t)b * 512 + c]));
      }
    }
    gsync(p.bar, ++ep);

    // ---- F: H1 = gelu(X3@W1), N=2048, 256 blocks (32ct x 8rt) ----
    if (blk < 256)
      gemm16(blk & 31, blk >> 5, p.X3, 512, p.W1, 2048, 512, nullptr, 0, p.H1, 2048, 0, 1);
    gsync(p.bar, ++ep);

    // ---- G: GP[ks] = H1[:,ks*512:+512] @ W2[ks*512:+512,:], split-K4, 256 blk ----
    if (blk < 256) {
      int ks = blk >> 6, loc = blk & 63;
      gemm16(loc & 7, loc >> 3, p.H1 + ks * 512, 2048,
             p.W2 + (size_t)ks * 512 * 512, 512, 512,
             nullptr, 0, p.GP + (size_t)ks * NB * 512, 512, 0, 0);
    }
    gsync(p.bar, ++ep);

    // ---- R: X = X3 + GP0+GP1+GP2+GP3 (fixed order); HID[s] = X ----
    if (blk < 256) {
      int el = blk * 256 + t;
      float v = ldsc(&p.X3[el])
              + ldsc(&p.GP[el]) + ldsc(&p.GP[NB*512 + el])
              + ldsc(&p.GP[2*NB*512 + el]) + ldsc(&p.GP[3*NB*512 + el]);
      stsc(&p.X[el], v);
      p.HID[(size_t)s * NB * 512 + el] = v;
    }
    gsync(p.bar, ++ep);

    // ---- H: logits + argmax partials; col tiles XCD-pinned (bx%8==blk%8) ----
    {
      const int x = blk & 7, idx2 = blk >> 3;
      const int ii = idx2 & 15, by = idx2 >> 4;
      const int bx = x + 8 * ii;
      if (bx < 125) logits_tile(bx, by);
    }
    gsync(p.bar, ++ep);
  }

  // ---- epilogue: state machine t=143 + final TOK/GEN/BND ----
  if (blk < 128 && (blk & 15) == 0) {
    const int b0 = (blk >> 4) * 16;
    state_phase(MAXTOK, b0, 1);
  }
}

// ======================= host ==============================================

extern "C" void kernel_launch(void* const* d_in, const int* in_sizes, int n_in,
                              void* d_out, int out_size, void* d_ws, size_t ws_size,
                              hipStream_t stream)
{
  const float* z_seq = (const float*)d_in[0];
  const float* z_w   = (const float*)d_in[1];
  const float* W_l2d = (const float*)d_in[2];
  const float* temb  = (const float*)d_in[3];
  const float* Wq  = (const float*)d_in[4];
  const float* Wk  = (const float*)d_in[5];
  const float* Wv  = (const float*)d_in[6];
  const float* Wo  = (const float*)d_in[7];
  const float* Wcq = (const float*)d_in[8];
  const float* Wck = (const float*)d_in[9];
  const float* Wcv = (const float*)d_in[10];
  const float* Wco = (const float*)d_in[11];
  const float* W1  = (const float*)d_in[12];
  const float* W2  = (const float*)d_in[13];
  const float* Wout= (const float*)d_in[14];

  float* fw = (float*)d_ws;
  size_t o = 4096;   // first 4096 words: barrier counters + go lines
  auto alloc = [&](size_t n) { float* r = fw + o; o += (n + 63) & ~(size_t)63; return r; };
  float* MCK = alloc((size_t)NB*KPH*NMEM*HD);
  float* MCV = alloc((size_t)NB*KPH*NMEM*HD);
  float* MEM = alloc((size_t)NB*KPH*NMEM*HD);   // reused as WCAT + GP/CQ2 after setup
  float* KC  = alloc((size_t)NB*CT*HD);
  float* VC  = alloc((size_t)NB*CT*HD);
  float* XS  = alloc((size_t)NB*1024);          // [XIN | SA]
  float* X2  = alloc((size_t)NB*HD);
  float* X3  = alloc((size_t)NB*HD);
  float* X   = alloc((size_t)NB*HD);
  float* Qb  = alloc((size_t)NB*HD);
  float* CQ  = alloc((size_t)NB*HD);
  float* H1  = alloc((size_t)NB*4*HD);
  float* WZ  = alloc((size_t)NB*KPH*LATENT);
  float* PV  = alloc((size_t)NB*125);
  float* GF  = alloc(2*NB);
  int* ib = (int*)alloc(0);
  size_t io = 0;
  auto ialloc = [&](size_t n) { int* r = ib + io; io += (n + 63) & ~(size_t)63; return r; };
  int* PI   = ialloc((size_t)NB*125);
  int* CUR  = ialloc(2*NB);
  int* TIP  = ialloc(2*NB);
  int* POS  = ialloc(2*NB);
  int* DONE = ialloc(2*NB);
  int* IPH  = ialloc(2*NB);
  int* NXT0 = ialloc(NB);
  int* ACT  = ialloc(NB*KPH);

  // MEM region (1,572,864 floats) layout after setup:
  //   [0 .. 524288)        WCAT = [Wcq ; Wo@Wcq]  (1024 x 512)
  //   [524288 .. 786432)   GP   (4 * NB * HD floats, split-K4 partials)
  //   [786432 .. 851968)   CQ2  (NB * HD floats, split-K2 partial)
  float* WCAT = MEM;
  float* GP   = MEM + (size_t)1024*512;
  float* CQ2  = GP  + (size_t)4*NB*HD;

  float* out_f = (float*)d_out;
  float* TOK  = out_f;
  float* GEN  = out_f + NB*MAXTOK;
  float* BND  = out_f + 2*NB*MAXTOK;
  float* HID  = out_f + 2*NB*MAXTOK + NB*KPH;

  // ---- one-time setup (plain kernels; dispatch boundaries give coherence) ----
  k_zero<<<16, 256, 0, stream>>>(fw, 4096);                               // barrier
  int nz = 2*NB*MAXTOK + NB*KPH;
  k_zero<<<(nz + 255)/256, 256, 0, stream>>>(out_f, nz);                  // tok/gen/bnd
  k_wz<<<(NB*KPH*LATENT + 255)/256, 256, 0, stream>>>(z_seq, z_w, WZ);
  k_gemm<<<dim3(64,12),256,0,stream>>>(WZ, 128, W_l2d, 4096, 128, MEM, 4096);
  k_gemm<<<dim3(8,96),256,0,stream>>>(MEM, 512, Wck, 512, 512, MCK, 512);
  k_gemm<<<dim3(8,96),256,0,stream>>>(MEM, 512, Wcv, 512, 512, MCV, 512);
  k_gemm<<<dim3(8,16),256,0,stream>>>(Wo, 512, Wcq, 512, 512, WCAT + (size_t)512*512, 512);
  k_copy<<<(512*512 + 255)/256, 256, 0, stream>>>(Wcq, WCAT, 512*512);
  k_init<<<1,128,0,stream>>>(z_w, CUR, TIP, POS, DONE, GF, IPH, NXT0, ACT);

  // ---- persistent decode: plain launch; 512 blocks, 2/CU co-resident ----
  DecP prm;
  prm.temb = temb; prm.Wq = Wq; prm.Wk = Wk; prm.Wv = Wv; prm.Wo = Wo;
  prm.Wco = Wco; prm.W1 = W1; prm.W2 = W2; prm.Wout = Wout;
  prm.MCK = MCK; prm.MCV = MCV; prm.WCAT = WCAT;
  prm.KC = KC; prm.VC = VC; prm.XS = XS; prm.X2 = X2; prm.X3 = X3; prm.X = X;
  prm.Qb = Qb; prm.CQ = CQ; prm.CQ2 = CQ2; prm.H1 = H1; prm.GP = GP;
  prm.PV = PV; prm.GF = GF;
  prm.PI = PI; prm.CUR = CUR; prm.TIP = TIP; prm.POS = POS; prm.DONE = DONE;
  prm.IPH = IPH; prm.NXT0 = NXT0; prm.ACT = ACT;
  prm.TOK = TOK; prm.GEN = GEN; prm.BND = BND; prm.HID = HID;
  prm.bar = (unsigned*)d_ws;

  k_decode<<<dim3(NBLK), dim3(256), 0, stream>>>(prm);
}